// Round 6
// baseline (544.266 us; speedup 1.0000x reference)
//
#include <hip/hip_runtime.h>
#include <math.h>

#define LL    1024
#define BB    16
#define NN1   2048      // 2*L
#define NNH   51200     // 50*L

__device__ __forceinline__ void fma4(float4& c, float a, const float4& w) {
    c.x = fmaf(a, w.x, c.x);
    c.y = fmaf(a, w.y, c.y);
    c.z = fmaf(a, w.z, c.z);
    c.w = fmaf(a, w.w, c.w);
}

// init accumulation targets: ypred = 0, z = b1 (bcast over batch), z2 = b2 (bcast)
__global__ void k_init(float* __restrict__ ypred, float* __restrict__ z,
                       float* __restrict__ z2,
                       const float* __restrict__ b1, const float* __restrict__ b2) {
    int i = blockIdx.x * blockDim.x + threadIdx.x;   // 0 .. BB*NNH-1 exactly
    if (i < BB * NN1) {
        ypred[i] = 0.0f;
        z2[i]    = b2[i & (NN1 - 1)];
    }
    z[i] = b1[i % NNH];
}

// K-split accumulating GEMM: out(BB,NCOL) += A(BB,KTOT)[m0:m0+CH] @ W(KTOT,NCOL)[m0:m0+CH]
// Thread owns 4 consecutive cols x all 16 batch rows (64 acc floats).
// __launch_bounds__(256,2) -> 128 VGPR cap: acc(64)+w(4..16)+a(16)+addr fits,
// no scratch spill (R4 failed at VGPR=52 w/ spills; R5's (256,4)=64 cap was borderline).
// W is read exactly ONCE per K-split block: no pair-sharing assumption.
template <int CH>
__global__ __launch_bounds__(256, 2) void k_gemm_acc(
        const float* __restrict__ A, const float* __restrict__ W,
        float* __restrict__ out, int KTOT, int NCOL) {
    __shared__ alignas(16) float as[CH][BB];         // [m][batch row]
    const int t  = threadIdx.x;
    const int n4 = blockIdx.x * 1024 + t * 4;
    const int m0 = blockIdx.y * CH;

    // stage A-tile transposed: lane t -> LDS addr t (bank t&31), conflict-free writes
    for (int l = t; l < CH * BB; l += 256) {
        int m = l >> 4, b = l & 15;
        as[m][b] = A[b * KTOT + m0 + m];
    }
    __syncthreads();

    float4 acc[BB];
#pragma unroll
    for (int r = 0; r < BB; ++r) acc[r] = make_float4(0.f, 0.f, 0.f, 0.f);

    const float* wp = W + (size_t)m0 * NCOL + n4;
#pragma unroll 4
    for (int m = 0; m < CH; ++m) {
        const float4 w = *(const float4*)wp;         // 16B/lane, coalesced 1KB/wave
        wp += NCOL;
#pragma unroll
        for (int q = 0; q < 4; ++q) {
            const float4 a = ((const float4*)as[m])[q];  // uniform addr -> LDS broadcast
            fma4(acc[4 * q + 0], a.x, w);
            fma4(acc[4 * q + 1], a.y, w);
            fma4(acc[4 * q + 2], a.z, w);
            fma4(acc[4 * q + 3], a.w, w);
        }
    }

#pragma unroll
    for (int r = 0; r < BB; ++r) {
        float* o = out + (size_t)r * NCOL + n4;
        atomicAdd(o + 0, acc[r].x);
        atomicAdd(o + 1, acc[r].y);
        atomicAdd(o + 2, acc[r].z);
        atomicAdd(o + 3, acc[r].w);
    }
}

__global__ void k_sigmoid(float* __restrict__ z) {
    int i = blockIdx.x * blockDim.x + threadIdx.x;
    float4 v = ((float4*)z)[i];
    v.x = 1.f / (1.f + __expf(-v.x));
    v.y = 1.f / (1.f + __expf(-v.y));
    v.z = 1.f / (1.f + __expf(-v.z));
    v.w = 1.f / (1.f + __expf(-v.w));
    ((float4*)z)[i] = v;
}

// out[b,i] = (1/L) * sum_j ( yr[j]*cos(2*pi*i*j/L) - yi[j]*sin(2*pi*i*j/L) )
// == sum_j amp*cos(arg+ph) of the reference, with exact mod-L phase reduction.
__global__ __launch_bounds__(256) void k_decode(const float* __restrict__ z2,
                                                float* __restrict__ out) {
    __shared__ float yr[LL], yi[LL];
    const int t = threadIdx.x;
    const int b = blockIdx.y;
    const int i = blockIdx.x * 256 + t;
    for (int j = t; j < LL; j += 256) {
        yr[j] = z2[b * NN1 + j];
        yi[j] = z2[b * NN1 + LL + j];
    }
    __syncthreads();
    float acc = 0.f;
    int r = 0;                                // r = (i*j) mod L, exact
    for (int j = 0; j < LL; ++j) {
        float rev = (float)r * (1.0f / LL);   // revolutions in [0,1)
        float c = __builtin_amdgcn_cosf(rev); // v_cos_f32: cos(2*pi*rev)
        float s = __builtin_amdgcn_sinf(rev); // v_sin_f32: sin(2*pi*rev)
        acc = fmaf(yr[j], c, acc);
        acc = fmaf(-yi[j], s, acc);
        r = (r + i) & (LL - 1);
    }
    out[b * LL + i] = acc * (1.0f / LL);
}

extern "C" void kernel_launch(void* const* d_in, const int* in_sizes, int n_in,
                              void* d_out, int out_size, void* d_ws, size_t ws_size,
                              hipStream_t stream) {
    const float* X  = (const float*)d_in[0];
    const float* Fc = (const float*)d_in[1];
    const float* W1 = (const float*)d_in[2];
    const float* b1 = (const float*)d_in[3];
    const float* W2 = (const float*)d_in[4];
    const float* b2 = (const float*)d_in[5];
    float* out = (float*)d_out;

    float* ws    = (float*)d_ws;
    float* ypred = ws;                 // BB*NN1  = 32768 f32
    float* z     = ypred + BB * NN1;   // BB*NNH  = 819200 f32 (h in-place after sigmoid)
    float* z2    = z + BB * NNH;       // BB*NN1  = 32768 f32   (total ws: 3.54 MB)

    // init accumulators (re-inits every call -> graph-replay safe)
    k_init<<<dim3((BB * NNH) / 256), 256, 0, stream>>>(ypred, z, z2, b1, b2);
    // y_pred = X @ Fc          : grid (2, 16)  = 32 blocks, CH=64
    k_gemm_acc<64><<<dim3(NN1 / 1024, LL / 64), 256, 0, stream>>>(X, Fc, ypred, LL, NN1);
    // z += y_pred @ W1         : grid (50, 16) = 800 blocks, CH=128  (419 MB stream)
    k_gemm_acc<128><<<dim3(NNH / 1024, NN1 / 128), 256, 0, stream>>>(ypred, W1, z, NN1, NNH);
    // h = sigmoid(z) in-place
    k_sigmoid<<<dim3((BB * NNH) / (256 * 4)), 256, 0, stream>>>(z);
    // z2 += h @ W2             : grid (2, 400) = 800 blocks, CH=128  (419 MB stream)
    k_gemm_acc<128><<<dim3(NN1 / 1024, NNH / 128), 256, 0, stream>>>(z, W2, z2, NNH, NN1);
    // decode (inverse-DFT form, exact mod-L phase)
    k_decode<<<dim3(LL / 256, BB), 256, 0, stream>>>(z2, out);
}

// Round 7
// 478.920 us; speedup vs baseline: 1.1364x; 1.1364x over previous
//
#include <hip/hip_runtime.h>
#include <math.h>

#define LL    1024
#define BB    16
#define NN1   2048      // 2*L
#define NNH   51200     // 50*L

// init accumulation targets: ypred = 0, z = b1 (bcast over batch), z2 = b2 (bcast)
__global__ void k_init(float* __restrict__ ypred, float* __restrict__ z,
                       float* __restrict__ z2,
                       const float* __restrict__ b1, const float* __restrict__ b2) {
    int i = blockIdx.x * blockDim.x + threadIdx.x;   // 0 .. BB*NNH-1 exactly
    if (i < BB * NN1) {
        ypred[i] = 0.0f;
        z2[i]    = b2[i & (NN1 - 1)];
    }
    z[i] = b1[i % NNH];
}

// K-split accumulating GEMM: out(BB,NCOL) += A(BB,KTOT)[m0:m0+CH] @ W(KTOT,NCOL)[m0:m0+CH]
// Thread tile: 2 consecutive cols x ALL 16 batch rows = 32 acc floats.
//  - W read EXACTLY once (no pair-blocks / cache-sharing assumptions).
//  - 32 accs: the 64-acc tile spilled twice (R4 VGPR=52, R6 VGPR=56 despite
//    128+ cap); 32 fits (~70 VGPR total).
//  - float2 W stream, unroll 8 -> 8 loads in flight/wave (4KB); (256,4) =>
//    16 waves/CU => 64KB/CU in flight, Little's-law sufficient for ~6 TB/s.
template <int CH>
__global__ __launch_bounds__(256, 4) void k_gemm_acc(
        const float* __restrict__ A, const float* __restrict__ W,
        float* __restrict__ out, int KTOT, int NCOL) {
    __shared__ alignas(16) float as[CH][BB];         // [m][batch row]
    const int t  = threadIdx.x;
    const int n2 = blockIdx.x * 512 + t * 2;
    const int m0 = blockIdx.y * CH;

    // stage A-tile transposed: thread t writes LDS word t -> bank t%32, conflict-free
    for (int l = t; l < CH * BB; l += 256) {
        int m = l >> 4, b = l & 15;
        as[m][b] = A[b * KTOT + m0 + m];
    }
    __syncthreads();

    float2 acc[BB];
#pragma unroll
    for (int r = 0; r < BB; ++r) acc[r] = make_float2(0.f, 0.f);

    const float* wp = W + (size_t)m0 * NCOL + n2;
#pragma unroll 8
    for (int m = 0; m < CH; ++m) {
        const float2 w = *(const float2*)wp;         // 8B/lane, coalesced 512B/wave
        wp += NCOL;
#pragma unroll
        for (int q = 0; q < 4; ++q) {
            const float4 a = ((const float4*)as[m])[q];  // uniform addr -> LDS broadcast
            acc[4 * q + 0].x = fmaf(a.x, w.x, acc[4 * q + 0].x);
            acc[4 * q + 0].y = fmaf(a.x, w.y, acc[4 * q + 0].y);
            acc[4 * q + 1].x = fmaf(a.y, w.x, acc[4 * q + 1].x);
            acc[4 * q + 1].y = fmaf(a.y, w.y, acc[4 * q + 1].y);
            acc[4 * q + 2].x = fmaf(a.z, w.x, acc[4 * q + 2].x);
            acc[4 * q + 2].y = fmaf(a.z, w.y, acc[4 * q + 2].y);
            acc[4 * q + 3].x = fmaf(a.w, w.x, acc[4 * q + 3].x);
            acc[4 * q + 3].y = fmaf(a.w, w.y, acc[4 * q + 3].y);
        }
    }

#pragma unroll
    for (int r = 0; r < BB; ++r) {
        float* o = out + (size_t)r * NCOL + n2;
        atomicAdd(o + 0, acc[r].x);
        atomicAdd(o + 1, acc[r].y);
    }
}

__global__ void k_sigmoid(float* __restrict__ z) {
    int i = blockIdx.x * blockDim.x + threadIdx.x;
    float4 v = ((float4*)z)[i];
    v.x = 1.f / (1.f + __expf(-v.x));
    v.y = 1.f / (1.f + __expf(-v.y));
    v.z = 1.f / (1.f + __expf(-v.z));
    v.w = 1.f / (1.f + __expf(-v.w));
    ((float4*)z)[i] = v;
}

// out[b,i] = (1/L) * sum_j ( yr[j]*cos(2*pi*i*j/L) - yi[j]*sin(2*pi*i*j/L) )
// == sum_j amp*cos(arg+ph) of the reference, with exact mod-L phase reduction.
__global__ __launch_bounds__(256) void k_decode(const float* __restrict__ z2,
                                                float* __restrict__ out) {
    __shared__ float yr[LL], yi[LL];
    const int t = threadIdx.x;
    const int b = blockIdx.y;
    const int i = blockIdx.x * 256 + t;
    for (int j = t; j < LL; j += 256) {
        yr[j] = z2[b * NN1 + j];
        yi[j] = z2[b * NN1 + LL + j];
    }
    __syncthreads();
    float acc = 0.f;
    int r = 0;                                // r = (i*j) mod L, exact
    for (int j = 0; j < LL; ++j) {
        float rev = (float)r * (1.0f / LL);   // revolutions in [0,1)
        float c = __builtin_amdgcn_cosf(rev); // v_cos_f32: cos(2*pi*rev)
        float s = __builtin_amdgcn_sinf(rev); // v_sin_f32: sin(2*pi*rev)
        acc = fmaf(yr[j], c, acc);
        acc = fmaf(-yi[j], s, acc);
        r = (r + i) & (LL - 1);
    }
    out[b * LL + i] = acc * (1.0f / LL);
}

extern "C" void kernel_launch(void* const* d_in, const int* in_sizes, int n_in,
                              void* d_out, int out_size, void* d_ws, size_t ws_size,
                              hipStream_t stream) {
    const float* X  = (const float*)d_in[0];
    const float* Fc = (const float*)d_in[1];
    const float* W1 = (const float*)d_in[2];
    const float* b1 = (const float*)d_in[3];
    const float* W2 = (const float*)d_in[4];
    const float* b2 = (const float*)d_in[5];
    float* out = (float*)d_out;

    float* ws    = (float*)d_ws;
    float* ypred = ws;                 // BB*NN1  = 32768 f32
    float* z     = ypred + BB * NN1;   // BB*NNH  = 819200 f32 (h in-place after sigmoid)
    float* z2    = z + BB * NNH;       // BB*NN1  = 32768 f32   (total ws: 3.54 MB)

    // init accumulators (re-inits every call -> graph-replay safe)
    k_init<<<dim3((BB * NNH) / 256), 256, 0, stream>>>(ypred, z, z2, b1, b2);
    // y_pred = X @ Fc          : grid (4, 8)   = 32 blocks,  CH=128
    k_gemm_acc<128><<<dim3(NN1 / 512, LL / 128), 256, 0, stream>>>(X, Fc, ypred, LL, NN1);
    // z += y_pred @ W1         : grid (100, 8) = 800 blocks, CH=256  (419 MB stream)
    k_gemm_acc<256><<<dim3(NNH / 512, NN1 / 256), 256, 0, stream>>>(ypred, W1, z, NN1, NNH);
    // h = sigmoid(z) in-place
    k_sigmoid<<<dim3((BB * NNH) / (256 * 4)), 256, 0, stream>>>(z);
    // z2 += h @ W2             : grid (4, 200) = 800 blocks, CH=256  (419 MB stream)
    k_gemm_acc<256><<<dim3(NN1 / 512, NNH / 256), 256, 0, stream>>>(z, W2, z2, NNH, NN1);
    // decode (inverse-DFT form, exact mod-L phase)
    k_decode<<<dim3(LL / 256, BB), 256, 0, stream>>>(z2, out);
}

// Round 8
// 284.234 us; speedup vs baseline: 1.9149x; 1.6850x over previous
//
#include <hip/hip_runtime.h>
#include <math.h>

#define LL    1024
#define BB    16
#define NN1   2048      // 2*L
#define NNH   51200     // 50*L

// ---------------- transpose X (16 x 1024) -> XT (1024 x 16) ----------------
__global__ void k_xt(const float* __restrict__ X, float* __restrict__ XT) {
    int id = blockIdx.x * 256 + threadIdx.x;     // 16384 total
    int n = id >> 4, b = id & 15;
    XT[id] = X[b * LL + n];
}

// ---------------- stage-1 K-split GEMM partials ----------------
// part[s][b][n] = sum_{m in split s} AT[m][b] * W[m][n]
// AT addresses are thread-uniform (no threadIdx) -> scalar-load eligible.
// W is a pure coalesced float2 stream with compile-time stride; 32 reg accs;
// no LDS, no barrier, no atomics anywhere in the loop.
template <int CH, int NCOL>
__global__ __launch_bounds__(256, 4) void k_gpart(
        const float* __restrict__ AT,    // [KTOT][16]
        const float* __restrict__ W,     // [KTOT][NCOL]
        float* __restrict__ part) {      // [splits][16][NCOL]
    const int t  = threadIdx.x;
    const int n2 = blockIdx.x * 512 + t * 2;
    const int s  = blockIdx.y;
    const int m0 = s * CH;

    float2 acc[BB];
#pragma unroll
    for (int r = 0; r < BB; ++r) acc[r] = make_float2(0.f, 0.f);

    const float* wp = W  + (size_t)m0 * NCOL + n2;
    const float* ap = AT + (size_t)m0 * BB;
#pragma unroll 4
    for (int m = 0; m < CH; ++m) {
        const float2 w = *(const float2*)wp;     // 8B/lane, 512B/wave, stride = const
        wp += NCOL;
        const float4 a0 = *(const float4*)(ap + 0);   // uniform addr (SGPR-able)
        const float4 a1 = *(const float4*)(ap + 4);
        const float4 a2 = *(const float4*)(ap + 8);
        const float4 a3 = *(const float4*)(ap + 12);
        ap += BB;
        acc[ 0].x = fmaf(a0.x, w.x, acc[ 0].x);  acc[ 0].y = fmaf(a0.x, w.y, acc[ 0].y);
        acc[ 1].x = fmaf(a0.y, w.x, acc[ 1].x);  acc[ 1].y = fmaf(a0.y, w.y, acc[ 1].y);
        acc[ 2].x = fmaf(a0.z, w.x, acc[ 2].x);  acc[ 2].y = fmaf(a0.z, w.y, acc[ 2].y);
        acc[ 3].x = fmaf(a0.w, w.x, acc[ 3].x);  acc[ 3].y = fmaf(a0.w, w.y, acc[ 3].y);
        acc[ 4].x = fmaf(a1.x, w.x, acc[ 4].x);  acc[ 4].y = fmaf(a1.x, w.y, acc[ 4].y);
        acc[ 5].x = fmaf(a1.y, w.x, acc[ 5].x);  acc[ 5].y = fmaf(a1.y, w.y, acc[ 5].y);
        acc[ 6].x = fmaf(a1.z, w.x, acc[ 6].x);  acc[ 6].y = fmaf(a1.z, w.y, acc[ 6].y);
        acc[ 7].x = fmaf(a1.w, w.x, acc[ 7].x);  acc[ 7].y = fmaf(a1.w, w.y, acc[ 7].y);
        acc[ 8].x = fmaf(a2.x, w.x, acc[ 8].x);  acc[ 8].y = fmaf(a2.x, w.y, acc[ 8].y);
        acc[ 9].x = fmaf(a2.y, w.x, acc[ 9].x);  acc[ 9].y = fmaf(a2.y, w.y, acc[ 9].y);
        acc[10].x = fmaf(a2.z, w.x, acc[10].x);  acc[10].y = fmaf(a2.z, w.y, acc[10].y);
        acc[11].x = fmaf(a2.w, w.x, acc[11].x);  acc[11].y = fmaf(a2.w, w.y, acc[11].y);
        acc[12].x = fmaf(a3.x, w.x, acc[12].x);  acc[12].y = fmaf(a3.x, w.y, acc[12].y);
        acc[13].x = fmaf(a3.y, w.x, acc[13].x);  acc[13].y = fmaf(a3.y, w.y, acc[13].y);
        acc[14].x = fmaf(a3.z, w.x, acc[14].x);  acc[14].y = fmaf(a3.z, w.y, acc[14].y);
        acc[15].x = fmaf(a3.w, w.x, acc[15].x);  acc[15].y = fmaf(a3.w, w.y, acc[15].y);
    }

    float* pp = part + ((size_t)s * BB) * NCOL + n2;
#pragma unroll
    for (int r = 0; r < BB; ++r)
        *(float2*)(pp + (size_t)r * NCOL) = acc[r];   // plain coalesced stores
}

// ---------------- reduce splits, output TRANSPOSED [N][16] ----------------
// outT[n][b] = op( bias[n] + sum_s part[s][b][n] ),  op = sigmoid if SIG
template <bool SIG>
__global__ __launch_bounds__(256) void k_redT(
        const float* __restrict__ part,   // [splits][16][N]
        const float* __restrict__ bias,   // [N] or nullptr
        float* __restrict__ outT,         // [N][16]
        int N, int splits) {
    const int n = blockIdx.x * 256 + threadIdx.x;
    float acc[BB];
#pragma unroll
    for (int b = 0; b < BB; ++b) acc[b] = 0.f;
    for (int s = 0; s < splits; ++s) {
        const float* p = part + ((size_t)s * BB) * N + n;
#pragma unroll
        for (int b = 0; b < BB; ++b) acc[b] += p[(size_t)b * N];   // 16 indep loads
    }
    const float bv = bias ? bias[n] : 0.f;
#pragma unroll
    for (int b = 0; b < BB; ++b) {
        float v = acc[b] + bv;
        if (SIG) v = 1.f / (1.f + __expf(-v));
        acc[b] = v;
    }
    float4* o = (float4*)(outT + (size_t)n * BB);    // 64B/thread contiguous
    o[0] = make_float4(acc[ 0], acc[ 1], acc[ 2], acc[ 3]);
    o[1] = make_float4(acc[ 4], acc[ 5], acc[ 6], acc[ 7]);
    o[2] = make_float4(acc[ 8], acc[ 9], acc[10], acc[11]);
    o[3] = make_float4(acc[12], acc[13], acc[14], acc[15]);
}

// ---------------- reduce splits, natural layout [16][NN1] ----------------
__global__ __launch_bounds__(256) void k_redN(
        const float* __restrict__ part,   // [splits][16][NN1]; [s][b][n] at s*32768+id
        const float* __restrict__ bias,   // [NN1]
        float* __restrict__ out,          // [16][NN1]
        int splits) {
    const int id = blockIdx.x * 256 + threadIdx.x;   // 32768
    const int n  = id & (NN1 - 1);
    float acc[4] = {0.f, 0.f, 0.f, 0.f};
#pragma unroll 8
    for (int s = 0; s < splits; ++s)
        acc[s & 3] += part[(size_t)s * (BB * NN1) + id];
    out[id] = (acc[0] + acc[1]) + (acc[2] + acc[3]) + bias[n];
}

// out[b,i] = (1/L) * sum_j ( yr[j]*cos(2*pi*i*j/L) - yi[j]*sin(2*pi*i*j/L) )
// == sum_j amp*cos(arg+ph) of the reference, with exact mod-L phase reduction.
__global__ __launch_bounds__(256) void k_decode(const float* __restrict__ z2,
                                                float* __restrict__ out) {
    __shared__ float yr[LL], yi[LL];
    const int t = threadIdx.x;
    const int b = blockIdx.y;
    const int i = blockIdx.x * 256 + t;
    for (int j = t; j < LL; j += 256) {
        yr[j] = z2[b * NN1 + j];
        yi[j] = z2[b * NN1 + LL + j];
    }
    __syncthreads();
    float acc = 0.f;
    int r = 0;                                // r = (i*j) mod L, exact
    for (int j = 0; j < LL; ++j) {
        float rev = (float)r * (1.0f / LL);   // revolutions in [0,1)
        float c = __builtin_amdgcn_cosf(rev); // v_cos_f32: cos(2*pi*rev)
        float s = __builtin_amdgcn_sinf(rev); // v_sin_f32: sin(2*pi*rev)
        acc = fmaf(yr[j], c, acc);
        acc = fmaf(-yi[j], s, acc);
        r = (r + i) & (LL - 1);
    }
    out[b * LL + i] = acc * (1.0f / LL);
}

extern "C" void kernel_launch(void* const* d_in, const int* in_sizes, int n_in,
                              void* d_out, int out_size, void* d_ws, size_t ws_size,
                              hipStream_t stream) {
    const float* X  = (const float*)d_in[0];
    const float* Fc = (const float*)d_in[1];
    const float* W1 = (const float*)d_in[2];
    const float* b1 = (const float*)d_in[3];
    const float* W2 = (const float*)d_in[4];
    const float* b2 = (const float*)d_in[5];
    float* out = (float*)d_out;

    // workspace layout (floats); every element is written before read each call
    float* ws     = (float*)d_ws;
    float* XT     = ws;                       //  1024*16      =    16384
    float* ypredT = XT     + LL * BB;         //  2048*16      =    32768
    float* hT     = ypredT + NN1 * BB;        // 51200*16      =   819200
    float* z2     = hT     + NNH * BB;        //    16*2048    =    32768
    float* parts0 = z2     + BB * NN1;        // 16*16*2048    =   524288
    float* parts1 = parts0 + 16 * BB * NN1;   // 16*16*51200   = 13107200
    float* parts2 = parts1 + 16 * BB * NNH;   // 400*16*2048   = 13107200
    // total ~27.7M floats = 111 MB  (<< ws_size, observed ~1.6 GB poison fill)

    // X^T
    k_xt<<<dim3(LL * BB / 256), 256, 0, stream>>>(X, XT);
    // y_pred^T = (X @ Fc)^T : CH=64 -> 16 splits, grid (4,16)=64 blocks
    k_gpart<64, NN1><<<dim3(NN1 / 512, 16), 256, 0, stream>>>(XT, Fc, parts0);
    k_redT<false><<<dim3(NN1 / 256), 256, 0, stream>>>(parts0, nullptr, ypredT, NN1, 16);
    // h^T = sigmoid(y_pred @ W1 + b1)^T : CH=128 -> 16 splits, grid (100,16)=1600 blocks
    k_gpart<128, NNH><<<dim3(NNH / 512, 16), 256, 0, stream>>>(ypredT, W1, parts1);
    k_redT<true><<<dim3(NNH / 256), 256, 0, stream>>>(parts1, b1, hT, NNH, 16);
    // z2 = h @ W2 + b2 : CH=128 -> 400 splits, grid (4,400)=1600 blocks
    k_gpart<128, NN1><<<dim3(NN1 / 512, 400), 256, 0, stream>>>(hT, W2, parts2);
    k_redN<<<dim3(BB * NN1 / 256), 256, 0, stream>>>(parts2, b2, z2, 400);
    // decode (inverse-DFT form, exact mod-L phase)
    k_decode<<<dim3(LL / 256, BB), 256, 0, stream>>>(z2, out);
}

// Round 9
// 236.460 us; speedup vs baseline: 2.3017x; 1.2020x over previous
//
#include <hip/hip_runtime.h>
#include <math.h>

#define LL    1024
#define BB    16
#define NN1   2048      // 2*L
#define NNH   51200     // 50*L

using f32x2 = __attribute__((ext_vector_type(2))) float;

// ---------------- transpose X (16 x 1024) -> XT (1024 x 16) ----------------
__global__ void k_xt(const float* __restrict__ X, float* __restrict__ XT) {
    int id = blockIdx.x * 256 + threadIdx.x;     // 16384 total
    int n = id >> 4, b = id & 15;
    XT[id] = X[b * LL + n];
}

// ---------------- stage-1 K-split GEMM partials ----------------
// part[s][b][n] = sum_{m in split s} AT[m][b] * W[m][n]
// AT addresses are thread-uniform -> scalar loads; W is a pure coalesced
// nontemporal float2 stream (single-use 419MB: keep it OUT of L3 so the
// 26MB partials stay resident for the reduce pass). 32 reg accs; no LDS,
// no barrier, no atomics.
template <int CH, int NCOL>
__global__ __launch_bounds__(256, 4) void k_gpart(
        const float* __restrict__ AT,    // [KTOT][16]
        const float* __restrict__ W,     // [KTOT][NCOL]
        float* __restrict__ part) {      // [splits][16][NCOL]
    const int t  = threadIdx.x;
    const int n2 = blockIdx.x * 512 + t * 2;
    const int s  = blockIdx.y;
    const int m0 = s * CH;

    float2 acc[BB];
#pragma unroll
    for (int r = 0; r < BB; ++r) acc[r] = make_float2(0.f, 0.f);

    const float* wp = W  + (size_t)m0 * NCOL + n2;
    const float* ap = AT + (size_t)m0 * BB;
#pragma unroll 8
    for (int m = 0; m < CH; ++m) {
        const f32x2 w = __builtin_nontemporal_load((const f32x2*)wp); // nt stream
        wp += NCOL;
        const float4 a0 = *(const float4*)(ap + 0);   // uniform addr (SGPR)
        const float4 a1 = *(const float4*)(ap + 4);
        const float4 a2 = *(const float4*)(ap + 8);
        const float4 a3 = *(const float4*)(ap + 12);
        ap += BB;
        acc[ 0].x = fmaf(a0.x, w.x, acc[ 0].x);  acc[ 0].y = fmaf(a0.x, w.y, acc[ 0].y);
        acc[ 1].x = fmaf(a0.y, w.x, acc[ 1].x);  acc[ 1].y = fmaf(a0.y, w.y, acc[ 1].y);
        acc[ 2].x = fmaf(a0.z, w.x, acc[ 2].x);  acc[ 2].y = fmaf(a0.z, w.y, acc[ 2].y);
        acc[ 3].x = fmaf(a0.w, w.x, acc[ 3].x);  acc[ 3].y = fmaf(a0.w, w.y, acc[ 3].y);
        acc[ 4].x = fmaf(a1.x, w.x, acc[ 4].x);  acc[ 4].y = fmaf(a1.x, w.y, acc[ 4].y);
        acc[ 5].x = fmaf(a1.y, w.x, acc[ 5].x);  acc[ 5].y = fmaf(a1.y, w.y, acc[ 5].y);
        acc[ 6].x = fmaf(a1.z, w.x, acc[ 6].x);  acc[ 6].y = fmaf(a1.z, w.y, acc[ 6].y);
        acc[ 7].x = fmaf(a1.w, w.x, acc[ 7].x);  acc[ 7].y = fmaf(a1.w, w.y, acc[ 7].y);
        acc[ 8].x = fmaf(a2.x, w.x, acc[ 8].x);  acc[ 8].y = fmaf(a2.x, w.y, acc[ 8].y);
        acc[ 9].x = fmaf(a2.y, w.x, acc[ 9].x);  acc[ 9].y = fmaf(a2.y, w.y, acc[ 9].y);
        acc[10].x = fmaf(a2.z, w.x, acc[10].x);  acc[10].y = fmaf(a2.z, w.y, acc[10].y);
        acc[11].x = fmaf(a2.w, w.x, acc[11].x);  acc[11].y = fmaf(a2.w, w.y, acc[11].y);
        acc[12].x = fmaf(a3.x, w.x, acc[12].x);  acc[12].y = fmaf(a3.x, w.y, acc[12].y);
        acc[13].x = fmaf(a3.y, w.x, acc[13].x);  acc[13].y = fmaf(a3.y, w.y, acc[13].y);
        acc[14].x = fmaf(a3.z, w.x, acc[14].x);  acc[14].y = fmaf(a3.z, w.y, acc[14].y);
        acc[15].x = fmaf(a3.w, w.x, acc[15].x);  acc[15].y = fmaf(a3.w, w.y, acc[15].y);
    }

    float* pp = part + ((size_t)s * BB) * NCOL + n2;
#pragma unroll
    for (int r = 0; r < BB; ++r)
        *(float2*)(pp + (size_t)r * NCOL) = acc[r];   // plain stores (want L3 residency)
}

// ---------------- reduce splits, output TRANSPOSED [N][16] ----------------
// outT[n][b] = op( bias[n] + sum_s part[s][b][n] ),  op = sigmoid if SIG
template <bool SIG>
__global__ __launch_bounds__(256) void k_redT(
        const float* __restrict__ part,   // [splits][16][N]
        const float* __restrict__ bias,   // [N] or nullptr
        float* __restrict__ outT,         // [N][16]
        int N, int splits) {
    const int n = blockIdx.x * 256 + threadIdx.x;
    float acc[BB];
#pragma unroll
    for (int b = 0; b < BB; ++b) acc[b] = 0.f;
    for (int s = 0; s < splits; ++s) {
        const float* p = part + ((size_t)s * BB) * N + n;
#pragma unroll
        for (int b = 0; b < BB; ++b) acc[b] += p[(size_t)b * N];   // 16 indep loads
    }
    const float bv = bias ? bias[n] : 0.f;
#pragma unroll
    for (int b = 0; b < BB; ++b) {
        float v = acc[b] + bv;
        if (SIG) v = 1.f / (1.f + __expf(-v));
        acc[b] = v;
    }
    float4* o = (float4*)(outT + (size_t)n * BB);    // 64B/thread contiguous
    o[0] = make_float4(acc[ 0], acc[ 1], acc[ 2], acc[ 3]);
    o[1] = make_float4(acc[ 4], acc[ 5], acc[ 6], acc[ 7]);
    o[2] = make_float4(acc[ 8], acc[ 9], acc[10], acc[11]);
    o[3] = make_float4(acc[12], acc[13], acc[14], acc[15]);
}

// ---------------- reduce splits, natural layout [16][NN1] ----------------
__global__ __launch_bounds__(256) void k_redN(
        const float* __restrict__ part,   // [splits][16][NN1]; [s][b][n] at s*32768+id
        const float* __restrict__ bias,   // [NN1]
        float* __restrict__ out,          // [16][NN1]
        int splits) {
    const int id = blockIdx.x * 256 + threadIdx.x;   // 32768
    const int n  = id & (NN1 - 1);
    float acc[4] = {0.f, 0.f, 0.f, 0.f};
#pragma unroll 8
    for (int s = 0; s < splits; ++s)
        acc[s & 3] += part[(size_t)s * (BB * NN1) + id];
    out[id] = (acc[0] + acc[1]) + (acc[2] + acc[3]) + bias[n];
}

// out[b,i] = (1/L) * sum_j ( yr[j]*cos(2*pi*i*j/L) - yi[j]*sin(2*pi*i*j/L) )
// Split the j-sum across 2 threads per output (t-high half does j=512..1023),
// pair-combined with one shfl_down: 2x the waves of the R7 version.
__global__ __launch_bounds__(512) void k_decode(const float* __restrict__ z2,
                                                float* __restrict__ out) {
    __shared__ float yr[LL], yi[LL];
    const int t   = threadIdx.x;
    const int b   = blockIdx.y;
    const int i   = blockIdx.x * 256 + (t & 255);
    const int jh  = t >> 8;                   // 0 or 1: which j-half
    for (int j = t; j < LL; j += 512) {
        yr[j] = z2[b * NN1 + j];
        yi[j] = z2[b * NN1 + LL + j];
    }
    __syncthreads();
    float acc = 0.f;
    int r = (jh * 512 * i) & (LL - 1);        // (i*j0) mod L, exact
    for (int j = 0; j < 512; ++j) {
        float rev = (float)r * (1.0f / LL);   // revolutions in [0,1)
        float c = __builtin_amdgcn_cosf(rev); // v_cos_f32: cos(2*pi*rev)
        float s = __builtin_amdgcn_sinf(rev); // v_sin_f32: sin(2*pi*rev)
        acc = fmaf(yr[jh * 512 + j], c, acc);
        acc = fmaf(-yi[jh * 512 + j], s, acc);
        r = (r + i) & (LL - 1);
    }
    // pair-combine across the two j-halves: lanes differ only in bit 8 of t,
    // which is bit 8 of the flat thread id -> different waves. Use LDS.
    __shared__ float partial[256];
    if (jh == 1) partial[t & 255] = acc;
    __syncthreads();
    if (jh == 0) out[b * LL + i] = (acc + partial[t]) * (1.0f / LL);
}

extern "C" void kernel_launch(void* const* d_in, const int* in_sizes, int n_in,
                              void* d_out, int out_size, void* d_ws, size_t ws_size,
                              hipStream_t stream) {
    const float* X  = (const float*)d_in[0];
    const float* Fc = (const float*)d_in[1];
    const float* W1 = (const float*)d_in[2];
    const float* b1 = (const float*)d_in[3];
    const float* W2 = (const float*)d_in[4];
    const float* b2 = (const float*)d_in[5];
    float* out = (float*)d_out;

    // workspace layout (floats); every element is written before read each call
    float* ws     = (float*)d_ws;
    float* XT     = ws;                       //  1024*16      =    16384
    float* ypredT = XT     + LL * BB;         //  2048*16      =    32768
    float* hT     = ypredT + NN1 * BB;        // 51200*16      =   819200
    float* z2     = hT     + NNH * BB;        //    16*2048    =    32768
    float* parts0 = z2     + BB * NN1;        // 16*16*2048    =   524288
    float* parts1 = parts0 + 16 * BB * NN1;   //  8*16*51200   =  6553600
    float* parts2 = parts1 + 8 * BB * NNH;    // 200*16*2048   =  6553600
    // total ~14.5M floats = 58 MB

    // X^T
    k_xt<<<dim3(LL * BB / 256), 256, 0, stream>>>(X, XT);
    // y_pred^T = (X @ Fc)^T : CH=64 -> 16 splits, grid (4,16)=64 blocks
    k_gpart<64, NN1><<<dim3(NN1 / 512, 16), 256, 0, stream>>>(XT, Fc, parts0);
    k_redT<false><<<dim3(NN1 / 256), 256, 0, stream>>>(parts0, nullptr, ypredT, NN1, 16);
    // h^T = sigmoid(y_pred @ W1 + b1)^T : CH=256 -> 8 splits, grid (100,8)=800 blocks
    k_gpart<256, NNH><<<dim3(NNH / 512, 8), 256, 0, stream>>>(ypredT, W1, parts1);
    k_redT<true><<<dim3(NNH / 256), 256, 0, stream>>>(parts1, b1, hT, NNH, 8);
    // z2 = h @ W2 + b2 : CH=256 -> 200 splits, grid (4,200)=800 blocks
    k_gpart<256, NN1><<<dim3(NN1 / 512, 200), 256, 0, stream>>>(hT, W2, parts2);
    k_redN<<<dim3(BB * NN1 / 256), 256, 0, stream>>>(parts2, b2, z2, 200);
    // decode (inverse-DFT form, exact mod-L phase; 2-way j-split)
    k_decode<<<dim3(LL / 256, BB), 512, 0, stream>>>(z2, out);
}